// Round 14
// baseline (543.343 us; speedup 1.0000x reference)
//
#include <hip/hip_runtime.h>
#include <hip/hip_bf16.h>
#include <stdint.h>

#define MAXDEG 64

typedef short s16x8 __attribute__((ext_vector_type(8)));
typedef short s16x4 __attribute__((ext_vector_type(4)));
typedef float f32x4 __attribute__((ext_vector_type(4)));

static __device__ __forceinline__ float us2f(unsigned short u) {
    union { float f; unsigned int i; } cv; cv.i = ((unsigned int)u) << 16; return cv.f;
}
static __device__ __forceinline__ unsigned short f2us(float f) {
    __hip_bfloat16 h = __float2bfloat16(f);   // RNE
    return *(unsigned short*)&h;
}

// ---------------- setup: degree + ELL adjacency (incoming edges per dst) ----------------
__global__ void k_build_ell(const int* __restrict__ ei, const float* __restrict__ ew,
                            float* __restrict__ deg, unsigned* __restrict__ cnt,
                            int2* __restrict__ ell, int E)
{
    int e = blockIdx.x * 256 + threadIdx.x;
    if (e >= E) return;
    int s = ei[e], d = ei[E + e];
    float w = ew[e];
    atomicAdd(&deg[d], w);
    unsigned slot = atomicAdd(&cnt[d], 1u);
    if (slot < MAXDEG) ell[(size_t)d * MAXDEG + slot] = make_int2(s, __float_as_int(w));
}

// ---- precompute edge norm rsqrt(deg_s+1)*w*rsqrt(deg_d+1) into ELL payload ----
__global__ void k_norm(int2* __restrict__ ell, const unsigned* __restrict__ cnt,
                       const float* __restrict__ deg, int N)
{
    int idx = blockIdx.x * 256 + threadIdx.x;
    if (idx >= N * MAXDEG) return;
    int n = idx >> 6;               // MAXDEG = 64
    int s = idx & (MAXDEG - 1);
    unsigned dg = cnt[n]; if (dg > MAXDEG) dg = MAXDEG;
    if ((unsigned)s >= dg) return;
    int2 p = ell[idx];
    unsigned sx = (unsigned)p.x;
    float nrm = (sx < (unsigned)N)
        ? rsqrtf(deg[sx] + 1.0f) * __int_as_float(p.y) * rsqrtf(deg[n] + 1.0f) : 0.f;
    ell[idx] = make_int2(p.x, __float_as_int(nrm));
}

// lane-L edge gather: 3 x ushort4 from a 1536B bf16 row + 12 fma
#define ACCE(NRM, V0, V1, V2)                                                          \
    a[0] = fmaf(NRM, us2f(V0.x), a[0]);  a[1] = fmaf(NRM, us2f(V0.y), a[1]);           \
    a[2] = fmaf(NRM, us2f(V0.z), a[2]);  a[3] = fmaf(NRM, us2f(V0.w), a[3]);           \
    a[4] = fmaf(NRM, us2f(V1.x), a[4]);  a[5] = fmaf(NRM, us2f(V1.y), a[5]);           \
    a[6] = fmaf(NRM, us2f(V1.z), a[6]);  a[7] = fmaf(NRM, us2f(V1.w), a[7]);           \
    a[8] = fmaf(NRM, us2f(V2.x), a[8]);  a[9] = fmaf(NRM, us2f(V2.y), a[9]);           \
    a[10] = fmaf(NRM, us2f(V2.z), a[10]); a[11] = fmaf(NRM, us2f(V2.w), a[11]);

#define EDGE_GATHER(P)                                                      \
    {                                                                       \
        unsigned sx = (unsigned)(P).x;                                      \
        if (sx >= (unsigned)N) sx = 0;        /* nrm already 0 (k_norm) */  \
        float nrm = __int_as_float((P).y);                                  \
        const unsigned short* qp = xw_in + (size_t)sx * 768 + L * 4;        \
        ushort4 w0 = *(const ushort4*)qp;                                   \
        ushort4 w1 = *(const ushort4*)(qp + 256);                           \
        ushort4 w2 = *(const ushort4*)(qp + 512);                           \
        ACCE(nrm, w0, w1, w2)                                               \
    }

// ---------------- layer A (MFMA, conv-as-3-shifted-GEMMs), wave work-stealing ----------
// Fixed co-resident grid; weights staged once per block; each wave fetches nodes from a
// global counter (lane0 atomicAdd + shfl broadcast) -> perfect balance, no drain.
template<int CIN>
__global__ __launch_bounds__(512, 4) void k_layer_a(
    const float* __restrict__ x_in,   // [T][N][CIN] f32
    const float* __restrict__ cw,     // [64][CIN][3] f32
    const float* __restrict__ gm, const float* __restrict__ bt,
    const float* __restrict__ gw,     // [64][64] f32
    unsigned short* __restrict__ xw_out, unsigned* __restrict__ ctr, int N)
{
    constexpr int KT   = CIN / 32;
    constexpr int WSTR = (CIN == 64) ? 72 : 40;
    __shared__ __align__(16) short WT[3 * 64 * WSTR];  // WT[kk][c][ci]
    __shared__ __align__(16) short gwT[64 * 72];       // gwT[d][cc]
    __shared__ __align__(16) short xh[8][14 * 72];

    const int tid = threadIdx.x;
    const int nn = tid >> 6;
    const int c = tid & 63;
    const int m = c & 15;
    const int q = c >> 4;
    const int mrow = (m < 12) ? m : 11;

    for (int g = tid; g < 3 * 64 * CIN; g += 512) {
        int kk = g / (64 * CIN);
        int r = g - kk * 64 * CIN;
        int cc = r / CIN, ci = r - cc * CIN;
        WT[kk * (64 * WSTR) + cc * WSTR + ci] = (short)f2us(cw[(cc * CIN + ci) * 3 + kk]);
    }
    for (int g = tid; g < 4096; g += 512) {
        int cc = g >> 6, d = g & 63;
        gwT[d * 72 + cc] = (short)f2us(gw[g]);
    }
    if (c < CIN) xh[nn][13 * 72 + c] = 0;      // bottom pad: never overwritten
    __syncthreads();

    for (;;) {
        unsigned n;
        if (c == 0) n = atomicAdd(ctr, 1u);
        n = (unsigned)__shfl((int)n, 0);
        if (n >= (unsigned)N) break;

        // stage x rows t=-1..12 -> rows 0..13 (row 0 re-zeroed: h overwrote it last iter)
        if (c < CIN) xh[nn][c] = 0;
        #pragma unroll
        for (int it = 0; it < (12 * CIN) / 64; ++it) {
            int i = it * 64 + c;
            int t = i / CIN, ci = i - t * CIN;
            xh[nn][(t + 1) * 72 + ci] = (short)f2us(x_in[((size_t)t * N + n) * CIN + ci]);
        }

        f32x4 acc[4];
        #pragma unroll
        for (int nt = 0; nt < 4; ++nt) acc[nt] = (f32x4){0.f, 0.f, 0.f, 0.f};
        #pragma unroll
        for (int kk = 0; kk < 3; ++kk) {
            #pragma unroll
            for (int kt = 0; kt < KT; ++kt) {
                s16x8 aA = *(const s16x8*)&xh[nn][(mrow + kk) * 72 + kt * 32 + q * 8];
                #pragma unroll
                for (int nt = 0; nt < 4; ++nt) {
                    s16x8 bB = *(const s16x8*)&WT[kk * (64 * WSTR) + (nt * 16 + m) * WSTR + kt * 32 + q * 8];
                    acc[nt] = __builtin_amdgcn_mfma_f32_16x16x32_bf16(aA, bB, acc[nt], 0, 0, 0);
                }
            }
        }

        #pragma unroll
        for (int nt = 0; nt < 4; ++nt) {
            float s  = acc[nt][0] + acc[nt][1] + acc[nt][2] + acc[nt][3];
            float s2 = acc[nt][0] * acc[nt][0] + acc[nt][1] * acc[nt][1]
                     + acc[nt][2] * acc[nt][2] + acc[nt][3] * acc[nt][3];
            if (q == 3) { s = 0.f; s2 = 0.f; }
            s  += __shfl_xor(s, 16);  s  += __shfl_xor(s, 32);
            s2 += __shfl_xor(s2, 16); s2 += __shfl_xor(s2, 32);
            const float mu  = s * (1.f / 12.f);
            const float var = s2 * (1.f / 12.f) - mu * mu;
            const float scn = rsqrtf(var + 1e-5f) * gm[nt * 16 + m];
            const float sbn = bt[nt * 16 + m];
            if (q < 3) {
                #pragma unroll
                for (int reg = 0; reg < 4; ++reg) {
                    float h = fmaf(acc[nt][reg] - mu, scn, sbn);
                    h = h > 0.f ? h : 0.f;
                    xh[nn][(q * 4 + reg) * 72 + nt * 16 + m] = (short)f2us(h);
                }
            }
        }

        s16x8 a2[2];
        #pragma unroll
        for (int kt2 = 0; kt2 < 2; ++kt2)
            a2[kt2] = *(const s16x8*)&xh[nn][mrow * 72 + kt2 * 32 + q * 8];
        f32x4 acc2[4];
        #pragma unroll
        for (int nt = 0; nt < 4; ++nt) acc2[nt] = (f32x4){0.f, 0.f, 0.f, 0.f};
        #pragma unroll
        for (int nt = 0; nt < 4; ++nt) {
            #pragma unroll
            for (int kt2 = 0; kt2 < 2; ++kt2) {
                s16x8 b2 = *(const s16x8*)&gwT[(nt * 16 + m) * 72 + kt2 * 32 + q * 8];
                acc2[nt] = __builtin_amdgcn_mfma_f32_16x16x32_bf16(a2[kt2], b2, acc2[nt], 0, 0, 0);
            }
        }

        unsigned short* dst = xw_out + (size_t)n * 768;
        if (q < 3) {
            #pragma unroll
            for (int nt = 0; nt < 4; ++nt)
                #pragma unroll
                for (int reg = 0; reg < 4; ++reg)
                    dst[(q * 4 + reg) * 64 + nt * 16 + m] = f2us(acc2[nt][reg]);
        }
    }
}

// ---------------- fused: layer-1 aggregation + layer-2 conv/IN/ReLU/gemm ---------------
// Wave work-stealing; emits only rowmean[n][64] = (1/12) sum_t xw2[n][t][:].
__global__ __launch_bounds__(512, 4) void k_gather_a(
    const unsigned short* __restrict__ xw_in,   // [N][768] bf16 (layer-1 xw)
    const int2* __restrict__ ell, const unsigned* __restrict__ cnt,
    const float* __restrict__ deg, const float* __restrict__ gb,   // gb1
    const float* __restrict__ cw,   // cw2 [64][64][3]
    const float* __restrict__ gm, const float* __restrict__ bt,    // gm2, bt2
    const float* __restrict__ gw,   // gw2 [64][64]
    unsigned short* __restrict__ rowmean, unsigned* __restrict__ ctr, int N)
{
    constexpr int WSTR = 72;
    __shared__ __align__(16) short WT[3 * 64 * WSTR];
    __shared__ __align__(16) short gwT[64 * 72];
    __shared__ __align__(16) short xh[8][14 * 72];

    const int tid = threadIdx.x;
    const int nn = tid >> 6;
    const int L = tid & 63;
    const int m = L & 15;
    const int q = L >> 4;
    const int mrow = (m < 12) ? m : 11;

    for (int g = tid; g < 3 * 64 * 64; g += 512) {
        int kk = g >> 12;
        int r = g & 4095;
        int cc = r >> 6, ci = r & 63;
        WT[kk * (64 * WSTR) + cc * WSTR + ci] = (short)f2us(cw[(cc * 64 + ci) * 3 + kk]);
    }
    for (int g = tid; g < 4096; g += 512) {
        int cc = g >> 6, d = g & 63;
        gwT[d * 72 + cc] = (short)f2us(gw[g]);
    }
    xh[nn][13 * 72 + L] = 0;                    // bottom pad: never overwritten
    __syncthreads();

    for (;;) {
        unsigned n;
        if (L == 0) n = atomicAdd(ctr, 1u);
        n = (unsigned)__shfl((int)n, 0);
        if (n >= (unsigned)N) break;

        // ---- gather: agg[t][c] for this node, in registers ----
        const float dn = rsqrtf(deg[n] + 1.0f);
        const float d2 = dn * dn;
        float a[12];
        {
            const unsigned short* self = xw_in + (size_t)n * 768 + L * 4;
            ushort4 v0 = *(const ushort4*)self;
            ushort4 v1 = *(const ushort4*)(self + 256);
            ushort4 v2 = *(const ushort4*)(self + 512);
            const int c0 = (L * 4) & 63;
            const float g0 = gb[c0], g1 = gb[c0 + 1], g2 = gb[c0 + 2], g3 = gb[c0 + 3];
            a[0] = fmaf(d2, us2f(v0.x), g0); a[1] = fmaf(d2, us2f(v0.y), g1);
            a[2] = fmaf(d2, us2f(v0.z), g2); a[3] = fmaf(d2, us2f(v0.w), g3);
            a[4] = fmaf(d2, us2f(v1.x), g0); a[5] = fmaf(d2, us2f(v1.y), g1);
            a[6] = fmaf(d2, us2f(v1.z), g2); a[7] = fmaf(d2, us2f(v1.w), g3);
            a[8] = fmaf(d2, us2f(v2.x), g0); a[9] = fmaf(d2, us2f(v2.y), g1);
            a[10] = fmaf(d2, us2f(v2.z), g2); a[11] = fmaf(d2, us2f(v2.w), g3);
        }
        unsigned dg = cnt[n]; if (dg > MAXDEG) dg = MAXDEG;
        const int2* row = ell + (size_t)n * MAXDEG;
        unsigned e = 0;
        for (; e + 4 <= dg; e += 4) {
            int2 p0 = row[e], p1 = row[e + 1], p2 = row[e + 2], p3 = row[e + 3];
            EDGE_GATHER(p0) EDGE_GATHER(p1) EDGE_GATHER(p2) EDGE_GATHER(p3)
        }
        for (; e < dg; ++e) { int2 p0 = row[e]; EDGE_GATHER(p0) }

        // ---- pack agg (bf16) into xh rows 1..12 (row 0 re-zeroed: h overwrote it) ----
        xh[nn][L] = 0;
        #pragma unroll
        for (int j = 0; j < 3; ++j) {
            s16x4 s4 = { (short)f2us(a[j * 4 + 0]), (short)f2us(a[j * 4 + 1]),
                         (short)f2us(a[j * 4 + 2]), (short)f2us(a[j * 4 + 3]) };
            *(s16x4*)&xh[nn][(j * 4 + q + 1) * 72 + ((L * 4) & 63)] = s4;
        }

        // ---- layer-2 conv (3 shifted GEMMs) ----
        f32x4 acc[4];
        #pragma unroll
        for (int nt = 0; nt < 4; ++nt) acc[nt] = (f32x4){0.f, 0.f, 0.f, 0.f};
        #pragma unroll
        for (int kk = 0; kk < 3; ++kk) {
            #pragma unroll
            for (int kt = 0; kt < 2; ++kt) {
                s16x8 aA = *(const s16x8*)&xh[nn][(mrow + kk) * 72 + kt * 32 + q * 8];
                #pragma unroll
                for (int nt = 0; nt < 4; ++nt) {
                    s16x8 bB = *(const s16x8*)&WT[kk * (64 * WSTR) + (nt * 16 + m) * WSTR + kt * 32 + q * 8];
                    acc[nt] = __builtin_amdgcn_mfma_f32_16x16x32_bf16(aA, bB, acc[nt], 0, 0, 0);
                }
            }
        }

        // ---- InstanceNorm + ReLU -> xh rows 0..11 ----
        #pragma unroll
        for (int nt = 0; nt < 4; ++nt) {
            float s  = acc[nt][0] + acc[nt][1] + acc[nt][2] + acc[nt][3];
            float s2 = acc[nt][0] * acc[nt][0] + acc[nt][1] * acc[nt][1]
                     + acc[nt][2] * acc[nt][2] + acc[nt][3] * acc[nt][3];
            if (q == 3) { s = 0.f; s2 = 0.f; }
            s  += __shfl_xor(s, 16);  s  += __shfl_xor(s, 32);
            s2 += __shfl_xor(s2, 16); s2 += __shfl_xor(s2, 32);
            const float mu  = s * (1.f / 12.f);
            const float var = s2 * (1.f / 12.f) - mu * mu;
            const float scn = rsqrtf(var + 1e-5f) * gm[nt * 16 + m];
            const float sbn = bt[nt * 16 + m];
            if (q < 3) {
                #pragma unroll
                for (int reg = 0; reg < 4; ++reg) {
                    float h = fmaf(acc[nt][reg] - mu, scn, sbn);
                    h = h > 0.f ? h : 0.f;
                    xh[nn][(q * 4 + reg) * 72 + nt * 16 + m] = (short)f2us(h);
                }
            }
        }

        // ---- gemm2: xw2 = h @ gw2 ----
        s16x8 a2[2];
        #pragma unroll
        for (int kt2 = 0; kt2 < 2; ++kt2)
            a2[kt2] = *(const s16x8*)&xh[nn][mrow * 72 + kt2 * 32 + q * 8];
        f32x4 acc2[4];
        #pragma unroll
        for (int nt = 0; nt < 4; ++nt) acc2[nt] = (f32x4){0.f, 0.f, 0.f, 0.f};
        #pragma unroll
        for (int nt = 0; nt < 4; ++nt) {
            #pragma unroll
            for (int kt2 = 0; kt2 < 2; ++kt2) {
                s16x8 b2 = *(const s16x8*)&gwT[(nt * 16 + m) * 72 + kt2 * 32 + q * 8];
                acc2[nt] = __builtin_amdgcn_mfma_f32_16x16x32_bf16(a2[kt2], b2, acc2[nt], 0, 0, 0);
            }
        }

        // ---- rowmean[n][d] = (1/12) * sum_{t<12} xw2[t][d] ----
        #pragma unroll
        for (int nt = 0; nt < 4; ++nt) {
            float pm = (q < 3) ? (acc2[nt][0] + acc2[nt][1] + acc2[nt][2] + acc2[nt][3]) : 0.f;
            pm += __shfl_xor(pm, 16); pm += __shfl_xor(pm, 32);
            if (q == 0)
                rowmean[(size_t)n * 64 + nt * 16 + m] = f2us(pm * (1.f / 12.f));
        }
    }
}

// ---------------- final: rowmean aggregation + 64x32 head ------------------------------
__global__ __launch_bounds__(256) void k_final(
    const unsigned short* __restrict__ rowmean, const int2* __restrict__ ell,
    const unsigned* __restrict__ cnt, const float* __restrict__ deg,
    const float* __restrict__ gb,
    const float* __restrict__ ow, const float* __restrict__ ob,
    float* __restrict__ dout, int N)
{
    __shared__ __align__(16) float hbuf[4][64];
    const int tid = threadIdx.x;
    const int nn = tid >> 6, L = tid & 63;
    int n = blockIdx.x * 4 + nn;
    if (n >= N) n = N - 1;
    const float dn = rsqrtf(deg[n] + 1.0f);
    const float d2 = dn * dn;

    float a = fmaf(d2, us2f(rowmean[(size_t)n * 64 + L]), gb[L]);

    unsigned dg = cnt[n]; if (dg > MAXDEG) dg = MAXDEG;
    const int2* row = ell + (size_t)n * MAXDEG;
    unsigned e = 0;
    for (; e + 8 <= dg; e += 8) {
        #pragma unroll
        for (int i = 0; i < 8; ++i) {
            int2 p = row[e + i];
            unsigned sx = (unsigned)p.x;
            if (sx >= (unsigned)N) sx = 0;            // nrm already 0
            a = fmaf(__int_as_float(p.y), us2f(rowmean[(size_t)sx * 64 + L]), a);
        }
    }
    for (; e < dg; ++e) {
        int2 p = row[e];
        unsigned sx = (unsigned)p.x;
        if (sx >= (unsigned)N) sx = 0;
        a = fmaf(__int_as_float(p.y), us2f(rowmean[(size_t)sx * 64 + L]), a);
    }

    hbuf[nn][L] = a;
    __syncthreads();
    if (L < 32) {
        float oa = ob[L];
        #pragma unroll
        for (int cc = 0; cc < 64; ++cc)
            oa = fmaf(hbuf[nn][cc], ow[cc * 32 + L], oa);
        dout[(size_t)n * 32 + L] = oa;
    }
}

extern "C" void kernel_launch(void* const* d_in, const int* in_sizes, int n_in,
                              void* d_out, int out_size, void* d_ws, size_t ws_size,
                              hipStream_t stream)
{
    const float* x   = (const float*)d_in[0];
    const int*   ei  = (const int*)d_in[1];
    const float* ew  = (const float*)d_in[2];
    const float* cw1 = (const float*)d_in[3];
    const float* gm1 = (const float*)d_in[5];
    const float* bt1 = (const float*)d_in[6];
    const float* gw1 = (const float*)d_in[7];
    const float* gb1 = (const float*)d_in[8];
    const float* cw2 = (const float*)d_in[9];
    const float* gm2 = (const float*)d_in[11];
    const float* bt2 = (const float*)d_in[12];
    const float* gw2 = (const float*)d_in[13];
    const float* gb2 = (const float*)d_in[14];
    const float* ow  = (const float*)d_in[15];
    const float* ob  = (const float*)d_in[16];

    const int N = in_sizes[0] / (12 * 32);
    const int E = in_sizes[2];

    // workspace layout: [ctrA, ctrG | pad..256] [deg N] [cnt N] | ell | bufXW1 | rowmean
    char* p0 = (char*)d_ws;
    unsigned* ctrA = (unsigned*)p0;
    unsigned* ctrG = (unsigned*)(p0 + 4);
    char* p = p0 + 256;
    float* deg = (float*)p;          p += (size_t)N * 4;
    unsigned* cnt = (unsigned*)p;    p += (size_t)N * 4;
    p = (char*)(((uintptr_t)p + 255) & ~(uintptr_t)255);
    int2* ell = (int2*)p;            p += (size_t)N * MAXDEG * 8;
    p = (char*)(((uintptr_t)p + 255) & ~(uintptr_t)255);
    unsigned short* bufXW1 = (unsigned short*)p; p += (size_t)N * 768 * 2;  // layer-1 xw
    unsigned short* rowmean = (unsigned short*)p; p += (size_t)N * 64 * 2;  // mean_t xw2

    const size_t need = (size_t)(p - p0);
    if (ws_size < need) {
        hipMemsetAsync(d_out, 0, (size_t)out_size * 4, stream);   // sentinel
        return;
    }

    // one memset zeroes counters + deg + cnt (contiguous from p0)
    hipMemsetAsync(p0, 0, 256 + (size_t)N * 8, stream);

    const int eb  = (E + 255) / 256;
    const int nb4 = (N + 3) / 4;
    k_build_ell<<<eb, 256, 0, stream>>>(ei, ew, deg, cnt, ell, E);
    k_norm<<<(N * MAXDEG + 255) / 256, 256, 0, stream>>>(ell, cnt, deg, N);

    // layer 1 (conv+IN+ReLU+gemm, MFMA, wave-stealing) -> bufXW1
    k_layer_a<32><<<1024, 512, 0, stream>>>(x, cw1, gm1, bt1, gw1, bufXW1, ctrA, N);
    // fused: layer-1 aggregation + layer-2 conv/IN/ReLU/gemm (wave-stealing) -> rowmean
    k_gather_a<<<768, 512, 0, stream>>>(bufXW1, ell, cnt, deg, gb1,
                                        cw2, gm2, bt2, gw2, rowmean, ctrG, N);
    // final: rowmean aggregation + head -> d_out
    k_final<<<nb4, 256, 0, stream>>>(rowmean, ell, cnt, deg, gb2, ow, ob, (float*)d_out, N);
}

// Round 15
// 196.655 us; speedup vs baseline: 2.7629x; 2.7629x over previous
//
#include <hip/hip_runtime.h>
#include <hip/hip_bf16.h>
#include <stdint.h>

#define MAXDEG 64

typedef short s16x8 __attribute__((ext_vector_type(8)));
typedef short s16x4 __attribute__((ext_vector_type(4)));
typedef float f32x4 __attribute__((ext_vector_type(4)));

static __device__ __forceinline__ float us2f(unsigned short u) {
    union { float f; unsigned int i; } cv; cv.i = ((unsigned int)u) << 16; return cv.f;
}
static __device__ __forceinline__ unsigned short f2us(float f) {
    __hip_bfloat16 h = __float2bfloat16(f);   // RNE
    return *(unsigned short*)&h;
}

// ---------------- setup: degree + ELL adjacency (incoming edges per dst) ----------------
__global__ void k_build_ell(const int* __restrict__ ei, const float* __restrict__ ew,
                            float* __restrict__ deg, unsigned* __restrict__ cnt,
                            int2* __restrict__ ell, int E)
{
    int e = blockIdx.x * 256 + threadIdx.x;
    if (e >= E) return;
    int s = ei[e], d = ei[E + e];
    float w = ew[e];
    atomicAdd(&deg[d], w);
    unsigned slot = atomicAdd(&cnt[d], 1u);
    if (slot < MAXDEG) ell[(size_t)d * MAXDEG + slot] = make_int2(s, __float_as_int(w));
}

// ---- edge norm into ELL payload; unused slots zero-filled (enables padded loops) ----
__global__ void k_norm(int2* __restrict__ ell, const unsigned* __restrict__ cnt,
                       const float* __restrict__ deg, int N)
{
    int idx = blockIdx.x * 256 + threadIdx.x;
    if (idx >= N * MAXDEG) return;
    int n = idx >> 6;               // MAXDEG = 64
    int s = idx & (MAXDEG - 1);
    unsigned dg = cnt[n]; if (dg > MAXDEG) dg = MAXDEG;
    int sxo = 0; float nrm = 0.f;
    if ((unsigned)s < dg) {
        int2 p = ell[idx];
        unsigned sx = (unsigned)p.x;
        if (sx < (unsigned)N) {
            nrm = rsqrtf(deg[sx] + 1.0f) * __int_as_float(p.y) * rsqrtf(deg[n] + 1.0f);
            sxo = p.x;
        }
    }
    ell[idx] = make_int2(sxo, __float_as_int(nrm));
}

// edge accumulate: 3 x ushort4 from a 1536B bf16 row + 12 fma (nrm==0 -> no-op)
static __device__ __forceinline__ void edge_acc(float* __restrict__ a, float nrm,
                                                const unsigned short* __restrict__ qp)
{
    ushort4 w0 = *(const ushort4*)qp;
    ushort4 w1 = *(const ushort4*)(qp + 256);
    ushort4 w2 = *(const ushort4*)(qp + 512);
    a[0] = fmaf(nrm, us2f(w0.x), a[0]);  a[1] = fmaf(nrm, us2f(w0.y), a[1]);
    a[2] = fmaf(nrm, us2f(w0.z), a[2]);  a[3] = fmaf(nrm, us2f(w0.w), a[3]);
    a[4] = fmaf(nrm, us2f(w1.x), a[4]);  a[5] = fmaf(nrm, us2f(w1.y), a[5]);
    a[6] = fmaf(nrm, us2f(w1.z), a[6]);  a[7] = fmaf(nrm, us2f(w1.w), a[7]);
    a[8] = fmaf(nrm, us2f(w2.x), a[8]);  a[9] = fmaf(nrm, us2f(w2.y), a[9]);
    a[10] = fmaf(nrm, us2f(w2.z), a[10]); a[11] = fmaf(nrm, us2f(w2.w), a[11]);
}

// ---------------- layer A (MFMA, conv-as-3-shifted-GEMMs), static, r13 ----------------
template<int CIN>
__global__ __launch_bounds__(512, 4) void k_layer_a(
    const float* __restrict__ x_in,   // [T][N][CIN] f32
    const float* __restrict__ cw,     // [64][CIN][3] f32
    const float* __restrict__ gm, const float* __restrict__ bt,
    const float* __restrict__ gw,     // [64][64] f32
    unsigned short* __restrict__ xw_out, int N)
{
    constexpr int KT   = CIN / 32;
    constexpr int WSTR = (CIN == 64) ? 72 : 40;
    __shared__ __align__(16) short WT[3 * 64 * WSTR];  // WT[kk][c][ci]
    __shared__ __align__(16) short gwT[64 * 72];       // gwT[d][cc]
    __shared__ __align__(16) short xh[8][14 * 72];

    const int tid = threadIdx.x;
    const int nn = tid >> 6;
    const int c = tid & 63;
    const int m = c & 15;
    const int q = c >> 4;
    const int mrow = (m < 12) ? m : 11;
    int n = blockIdx.x * 8 + nn;
    if (n >= N) n = N - 1;

    for (int g = tid; g < 3 * 64 * CIN; g += 512) {
        int kk = g / (64 * CIN);
        int r = g - kk * 64 * CIN;
        int cc = r / CIN, ci = r - cc * CIN;
        WT[kk * (64 * WSTR) + cc * WSTR + ci] = (short)f2us(cw[(cc * CIN + ci) * 3 + kk]);
    }
    for (int g = tid; g < 4096; g += 512) {
        int cc = g >> 6, d = g & 63;
        gwT[d * 72 + cc] = (short)f2us(gw[g]);
    }
    #pragma unroll
    for (int it = 0; it < (12 * CIN) / 64; ++it) {
        int i = it * 64 + c;
        int t = i / CIN, ci = i - t * CIN;
        xh[nn][(t + 1) * 72 + ci] = (short)f2us(x_in[((size_t)t * N + n) * CIN + ci]);
    }
    if (c < CIN) { xh[nn][c] = 0; xh[nn][13 * 72 + c] = 0; }
    __syncthreads();

    f32x4 acc[4];
    #pragma unroll
    for (int nt = 0; nt < 4; ++nt) acc[nt] = (f32x4){0.f, 0.f, 0.f, 0.f};
    #pragma unroll
    for (int kk = 0; kk < 3; ++kk) {
        #pragma unroll
        for (int kt = 0; kt < KT; ++kt) {
            s16x8 aA = *(const s16x8*)&xh[nn][(mrow + kk) * 72 + kt * 32 + q * 8];
            #pragma unroll
            for (int nt = 0; nt < 4; ++nt) {
                s16x8 bB = *(const s16x8*)&WT[kk * (64 * WSTR) + (nt * 16 + m) * WSTR + kt * 32 + q * 8];
                acc[nt] = __builtin_amdgcn_mfma_f32_16x16x32_bf16(aA, bB, acc[nt], 0, 0, 0);
            }
        }
    }

    #pragma unroll
    for (int nt = 0; nt < 4; ++nt) {
        float s  = acc[nt][0] + acc[nt][1] + acc[nt][2] + acc[nt][3];
        float s2 = acc[nt][0] * acc[nt][0] + acc[nt][1] * acc[nt][1]
                 + acc[nt][2] * acc[nt][2] + acc[nt][3] * acc[nt][3];
        if (q == 3) { s = 0.f; s2 = 0.f; }
        s  += __shfl_xor(s, 16);  s  += __shfl_xor(s, 32);
        s2 += __shfl_xor(s2, 16); s2 += __shfl_xor(s2, 32);
        const float mu  = s * (1.f / 12.f);
        const float var = s2 * (1.f / 12.f) - mu * mu;
        const float scn = rsqrtf(var + 1e-5f) * gm[nt * 16 + m];
        const float sbn = bt[nt * 16 + m];
        if (q < 3) {
            #pragma unroll
            for (int reg = 0; reg < 4; ++reg) {
                float h = fmaf(acc[nt][reg] - mu, scn, sbn);
                h = h > 0.f ? h : 0.f;
                xh[nn][(q * 4 + reg) * 72 + nt * 16 + m] = (short)f2us(h);
            }
        }
    }

    s16x8 a2[2];
    #pragma unroll
    for (int kt2 = 0; kt2 < 2; ++kt2)
        a2[kt2] = *(const s16x8*)&xh[nn][mrow * 72 + kt2 * 32 + q * 8];
    f32x4 acc2[4];
    #pragma unroll
    for (int nt = 0; nt < 4; ++nt) acc2[nt] = (f32x4){0.f, 0.f, 0.f, 0.f};
    #pragma unroll
    for (int nt = 0; nt < 4; ++nt) {
        #pragma unroll
        for (int kt2 = 0; kt2 < 2; ++kt2) {
            s16x8 b2 = *(const s16x8*)&gwT[(nt * 16 + m) * 72 + kt2 * 32 + q * 8];
            acc2[nt] = __builtin_amdgcn_mfma_f32_16x16x32_bf16(a2[kt2], b2, acc2[nt], 0, 0, 0);
        }
    }

    unsigned short* dst = xw_out + (size_t)n * 768;
    if (q < 3) {
        #pragma unroll
        for (int nt = 0; nt < 4; ++nt)
            #pragma unroll
            for (int reg = 0; reg < 4; ++reg)
                dst[(q * 4 + reg) * 64 + nt * 16 + m] = f2us(acc2[nt][reg]);
    }
}

// ---------------- fused: layer-1 aggregation + layer-2 conv/IN/ReLU/gemm ---------------
// TWO nodes per wave (16/block, grid 625 -> fully co-resident at 3 blocks/CU): the two
// independent edge streams double outstanding gather loads (latency hiding). Padded ELL
// entries have nrm=0 -> fma no-ops. Emits rowmean[n][64] = (1/12) sum_t xw2[n][t][:].
__global__ __launch_bounds__(512, 4) void k_gather_a(
    const unsigned short* __restrict__ xw_in,   // [N][768] bf16 (layer-1 xw)
    const int2* __restrict__ ell, const unsigned* __restrict__ cnt,
    const float* __restrict__ deg, const float* __restrict__ gb,   // gb1
    const float* __restrict__ cw,   // cw2 [64][64][3]
    const float* __restrict__ gm, const float* __restrict__ bt,    // gm2, bt2
    const float* __restrict__ gw,   // gw2 [64][64]
    unsigned short* __restrict__ rowmean, int N)
{
    constexpr int WSTR = 72;
    __shared__ __align__(16) short WT[3 * 64 * WSTR];
    __shared__ __align__(16) short gwT[64 * 72];
    __shared__ __align__(16) short xh[8][14 * 72];

    const int tid = threadIdx.x;
    const int nn = tid >> 6;
    const int L = tid & 63;
    const int m = L & 15;
    const int q = L >> 4;
    const int mrow = (m < 12) ? m : 11;

    for (int g = tid; g < 3 * 64 * 64; g += 512) {
        int kk = g >> 12;
        int r = g & 4095;
        int cc = r >> 6, ci = r & 63;
        WT[kk * (64 * WSTR) + cc * WSTR + ci] = (short)f2us(cw[(cc * 64 + ci) * 3 + kk]);
    }
    for (int g = tid; g < 4096; g += 512) {
        int cc = g >> 6, d = g & 63;
        gwT[d * 72 + cc] = (short)f2us(gw[g]);
    }
    xh[nn][13 * 72 + L] = 0;                    // bottom pad: never overwritten
    __syncthreads();

    int base = blockIdx.x * 16 + nn * 2;
    unsigned nP[2];
    nP[0] = (unsigned)((base     < N) ? base     : N - 1);
    nP[1] = (unsigned)((base + 1 < N) ? base + 1 : N - 1);

    // ---- gather both nodes' agg[t][c] in registers (interleaved edge streams) ----
    float aP[2][12];
    #pragma unroll
    for (int j = 0; j < 2; ++j) {
        const unsigned n = nP[j];
        const float dn = rsqrtf(deg[n] + 1.0f);
        const float d2 = dn * dn;
        const unsigned short* self = xw_in + (size_t)n * 768 + L * 4;
        ushort4 v0 = *(const ushort4*)self;
        ushort4 v1 = *(const ushort4*)(self + 256);
        ushort4 v2 = *(const ushort4*)(self + 512);
        const int c0 = (L * 4) & 63;
        const float g0 = gb[c0], g1 = gb[c0 + 1], g2 = gb[c0 + 2], g3 = gb[c0 + 3];
        float* a = aP[j];
        a[0] = fmaf(d2, us2f(v0.x), g0); a[1] = fmaf(d2, us2f(v0.y), g1);
        a[2] = fmaf(d2, us2f(v0.z), g2); a[3] = fmaf(d2, us2f(v0.w), g3);
        a[4] = fmaf(d2, us2f(v1.x), g0); a[5] = fmaf(d2, us2f(v1.y), g1);
        a[6] = fmaf(d2, us2f(v1.z), g2); a[7] = fmaf(d2, us2f(v1.w), g3);
        a[8] = fmaf(d2, us2f(v2.x), g0); a[9] = fmaf(d2, us2f(v2.y), g1);
        a[10] = fmaf(d2, us2f(v2.z), g2); a[11] = fmaf(d2, us2f(v2.w), g3);
    }
    {
        unsigned dg0 = cnt[nP[0]]; if (dg0 > MAXDEG) dg0 = MAXDEG;
        unsigned dg1 = cnt[nP[1]]; if (dg1 > MAXDEG) dg1 = MAXDEG;
        unsigned dgm = dg0 > dg1 ? dg0 : dg1;   // padded slots have nrm=0 -> no-op
        const int2* r0 = ell + (size_t)nP[0] * MAXDEG;
        const int2* r1 = ell + (size_t)nP[1] * MAXDEG;
        unsigned e = 0;
        for (; e + 2 <= dgm; e += 2) {
            int2 p00 = r0[e], p01 = r0[e + 1], p10 = r1[e], p11 = r1[e + 1];
            edge_acc(aP[0], __int_as_float(p00.y), xw_in + (size_t)(unsigned)p00.x * 768 + L * 4);
            edge_acc(aP[1], __int_as_float(p10.y), xw_in + (size_t)(unsigned)p10.x * 768 + L * 4);
            edge_acc(aP[0], __int_as_float(p01.y), xw_in + (size_t)(unsigned)p01.x * 768 + L * 4);
            edge_acc(aP[1], __int_as_float(p11.y), xw_in + (size_t)(unsigned)p11.x * 768 + L * 4);
        }
        if (e < dgm) {
            int2 p00 = r0[e], p10 = r1[e];
            edge_acc(aP[0], __int_as_float(p00.y), xw_in + (size_t)(unsigned)p00.x * 768 + L * 4);
            edge_acc(aP[1], __int_as_float(p10.y), xw_in + (size_t)(unsigned)p10.x * 768 + L * 4);
        }
    }

    // ---- per node: pack -> conv -> IN/ReLU -> gemm2 -> rowmean ----
    #pragma unroll
    for (int j = 0; j < 2; ++j) {
        const unsigned n = nP[j];
        const float* a = aP[j];

        xh[nn][L] = 0;    // row 0 re-zeroed (h overwrote it on previous node)
        #pragma unroll
        for (int j3 = 0; j3 < 3; ++j3) {
            s16x4 s4 = { (short)f2us(a[j3 * 4 + 0]), (short)f2us(a[j3 * 4 + 1]),
                         (short)f2us(a[j3 * 4 + 2]), (short)f2us(a[j3 * 4 + 3]) };
            *(s16x4*)&xh[nn][(j3 * 4 + q + 1) * 72 + ((L * 4) & 63)] = s4;
        }

        f32x4 acc[4];
        #pragma unroll
        for (int nt = 0; nt < 4; ++nt) acc[nt] = (f32x4){0.f, 0.f, 0.f, 0.f};
        #pragma unroll
        for (int kk = 0; kk < 3; ++kk) {
            #pragma unroll
            for (int kt = 0; kt < 2; ++kt) {
                s16x8 aA = *(const s16x8*)&xh[nn][(mrow + kk) * 72 + kt * 32 + q * 8];
                #pragma unroll
                for (int nt = 0; nt < 4; ++nt) {
                    s16x8 bB = *(const s16x8*)&WT[kk * (64 * WSTR) + (nt * 16 + m) * WSTR + kt * 32 + q * 8];
                    acc[nt] = __builtin_amdgcn_mfma_f32_16x16x32_bf16(aA, bB, acc[nt], 0, 0, 0);
                }
            }
        }

        #pragma unroll
        for (int nt = 0; nt < 4; ++nt) {
            float s  = acc[nt][0] + acc[nt][1] + acc[nt][2] + acc[nt][3];
            float s2 = acc[nt][0] * acc[nt][0] + acc[nt][1] * acc[nt][1]
                     + acc[nt][2] * acc[nt][2] + acc[nt][3] * acc[nt][3];
            if (q == 3) { s = 0.f; s2 = 0.f; }
            s  += __shfl_xor(s, 16);  s  += __shfl_xor(s, 32);
            s2 += __shfl_xor(s2, 16); s2 += __shfl_xor(s2, 32);
            const float mu  = s * (1.f / 12.f);
            const float var = s2 * (1.f / 12.f) - mu * mu;
            const float scn = rsqrtf(var + 1e-5f) * gm[nt * 16 + m];
            const float sbn = bt[nt * 16 + m];
            if (q < 3) {
                #pragma unroll
                for (int reg = 0; reg < 4; ++reg) {
                    float h = fmaf(acc[nt][reg] - mu, scn, sbn);
                    h = h > 0.f ? h : 0.f;
                    xh[nn][(q * 4 + reg) * 72 + nt * 16 + m] = (short)f2us(h);
                }
            }
        }

        s16x8 a2[2];
        #pragma unroll
        for (int kt2 = 0; kt2 < 2; ++kt2)
            a2[kt2] = *(const s16x8*)&xh[nn][mrow * 72 + kt2 * 32 + q * 8];
        f32x4 acc2[4];
        #pragma unroll
        for (int nt = 0; nt < 4; ++nt) acc2[nt] = (f32x4){0.f, 0.f, 0.f, 0.f};
        #pragma unroll
        for (int nt = 0; nt < 4; ++nt) {
            #pragma unroll
            for (int kt2 = 0; kt2 < 2; ++kt2) {
                s16x8 b2 = *(const s16x8*)&gwT[(nt * 16 + m) * 72 + kt2 * 32 + q * 8];
                acc2[nt] = __builtin_amdgcn_mfma_f32_16x16x32_bf16(a2[kt2], b2, acc2[nt], 0, 0, 0);
            }
        }

        #pragma unroll
        for (int nt = 0; nt < 4; ++nt) {
            float pm = (q < 3) ? (acc2[nt][0] + acc2[nt][1] + acc2[nt][2] + acc2[nt][3]) : 0.f;
            pm += __shfl_xor(pm, 16); pm += __shfl_xor(pm, 32);
            if (q == 0)
                rowmean[(size_t)n * 64 + nt * 16 + m] = f2us(pm * (1.f / 12.f));
        }
    }
}

// ---------------- final: rowmean aggregation + 64x32 head ------------------------------
__global__ __launch_bounds__(256) void k_final(
    const unsigned short* __restrict__ rowmean, const int2* __restrict__ ell,
    const unsigned* __restrict__ cnt, const float* __restrict__ deg,
    const float* __restrict__ gb,
    const float* __restrict__ ow, const float* __restrict__ ob,
    float* __restrict__ dout, int N)
{
    __shared__ __align__(16) float hbuf[4][64];
    const int tid = threadIdx.x;
    const int nn = tid >> 6, L = tid & 63;
    int n = blockIdx.x * 4 + nn;
    if (n >= N) n = N - 1;
    const float dn = rsqrtf(deg[n] + 1.0f);
    const float d2 = dn * dn;

    float a = fmaf(d2, us2f(rowmean[(size_t)n * 64 + L]), gb[L]);

    unsigned dg = cnt[n]; if (dg > MAXDEG) dg = MAXDEG;
    const int2* row = ell + (size_t)n * MAXDEG;
    unsigned e = 0;
    for (; e + 8 <= dg; e += 8) {
        #pragma unroll
        for (int i = 0; i < 8; ++i) {
            int2 p = row[e + i];
            a = fmaf(__int_as_float(p.y), us2f(rowmean[(size_t)(unsigned)p.x * 64 + L]), a);
        }
    }
    for (; e < dg; ++e) {
        int2 p = row[e];
        a = fmaf(__int_as_float(p.y), us2f(rowmean[(size_t)(unsigned)p.x * 64 + L]), a);
    }

    hbuf[nn][L] = a;
    __syncthreads();
    if (L < 32) {
        float oa = ob[L];
        #pragma unroll
        for (int cc = 0; cc < 64; ++cc)
            oa = fmaf(hbuf[nn][cc], ow[cc * 32 + L], oa);
        dout[(size_t)n * 32 + L] = oa;
    }
}

extern "C" void kernel_launch(void* const* d_in, const int* in_sizes, int n_in,
                              void* d_out, int out_size, void* d_ws, size_t ws_size,
                              hipStream_t stream)
{
    const float* x   = (const float*)d_in[0];
    const int*   ei  = (const int*)d_in[1];
    const float* ew  = (const float*)d_in[2];
    const float* cw1 = (const float*)d_in[3];
    const float* gm1 = (const float*)d_in[5];
    const float* bt1 = (const float*)d_in[6];
    const float* gw1 = (const float*)d_in[7];
    const float* gb1 = (const float*)d_in[8];
    const float* cw2 = (const float*)d_in[9];
    const float* gm2 = (const float*)d_in[11];
    const float* bt2 = (const float*)d_in[12];
    const float* gw2 = (const float*)d_in[13];
    const float* gb2 = (const float*)d_in[14];
    const float* ow  = (const float*)d_in[15];
    const float* ob  = (const float*)d_in[16];

    const int N = in_sizes[0] / (12 * 32);
    const int E = in_sizes[2];

    // workspace layout
    char* p0 = (char*)d_ws;
    char* p = p0;
    float* deg = (float*)p;          p += (size_t)N * 4;
    unsigned* cnt = (unsigned*)p;    p += (size_t)N * 4;   // adjacent to deg: one memset
    p = (char*)(((uintptr_t)p + 255) & ~(uintptr_t)255);
    int2* ell = (int2*)p;            p += (size_t)N * MAXDEG * 8;
    p = (char*)(((uintptr_t)p + 255) & ~(uintptr_t)255);
    unsigned short* bufXW1 = (unsigned short*)p; p += (size_t)N * 768 * 2;  // layer-1 xw
    unsigned short* rowmean = (unsigned short*)p; p += (size_t)N * 64 * 2;  // mean_t xw2

    const size_t need = (size_t)(p - p0);
    if (ws_size < need) {
        hipMemsetAsync(d_out, 0, (size_t)out_size * 4, stream);   // sentinel
        return;
    }

    hipMemsetAsync(deg, 0, (size_t)N * 8, stream);

    const int eb   = (E + 255) / 256;
    const int nb8  = (N + 7) / 8;
    const int nb16 = (N + 15) / 16;
    const int nb4  = (N + 3) / 4;
    k_build_ell<<<eb, 256, 0, stream>>>(ei, ew, deg, cnt, ell, E);
    k_norm<<<(N * MAXDEG + 255) / 256, 256, 0, stream>>>(ell, cnt, deg, N);

    // layer 1 (conv+IN+ReLU+gemm, MFMA) -> bufXW1
    k_layer_a<32><<<nb8, 512, 0, stream>>>(x, cw1, gm1, bt1, gw1, bufXW1, N);
    // fused: layer-1 aggregation + layer-2 conv/IN/ReLU/gemm (2 nodes/wave) -> rowmean
    k_gather_a<<<nb16, 512, 0, stream>>>(bufXW1, ell, cnt, deg, gb1,
                                         cw2, gm2, bt2, gw2, rowmean, N);
    // final: rowmean aggregation + head -> d_out
    k_final<<<nb4, 256, 0, stream>>>(rowmean, ell, cnt, deg, gb2, ow, ob, (float*)d_out, N);
}